// Round 3
// baseline (1374.071 us; speedup 1.0000x reference)
//
#include <hip/hip_runtime.h>
#include <stdint.h>
#include <math.h>

#define NN 32768      // total nodes
#define EE 262144     // edges per edge set (before self loops)
#define DD 128
#define NPG 1024
#define NB 32
#define CAPE 20       // per-dst LDS cache of edge activations (fallback beyond)
#define NEG_SLOPE 0.2f
// Round 1: partitionable w/ word0 draw -> wrong index1 (777). Round 2: legacy
// iota-split -> wrong index1 (756). Output 0 always passes => numerics right,
// RNG extraction wrong. Fix: partitionable 32-bit draws are bits1 ^ bits2
// (XOR fold of both cipher words) per _threefry_random_bits_partitionable.
#define USE_PARTITIONABLE 1

// ---------------- threefry2x32 (exact JAX algorithm) ----------------
__host__ __device__ inline void tf2x32(uint32_t k0, uint32_t k1, uint32_t c0, uint32_t c1,
                                       uint32_t* o0, uint32_t* o1) {
  uint32_t ks2 = k0 ^ k1 ^ 0x1BD11BDAu;
  uint32_t x0 = c0 + k0;
  uint32_t x1 = c1 + k1;
#define TFR(r) { x0 += x1; x1 = (x1 << (r)) | (x1 >> (32 - (r))); x1 ^= x0; }
  TFR(13) TFR(15) TFR(26) TFR(6)
  x0 += k1; x1 += ks2 + 1u;
  TFR(17) TFR(29) TFR(16) TFR(24)
  x0 += ks2; x1 += k0 + 2u;
  TFR(13) TFR(15) TFR(26) TFR(6)
  x0 += k0; x1 += k1 + 3u;
  TFR(17) TFR(29) TFR(16) TFR(24)
  x0 += k1; x1 += ks2 + 4u;
  TFR(13) TFR(15) TFR(26) TFR(6)
  x0 += ks2; x1 += k0 + 5u;
#undef TFR
  *o0 = x0; *o1 = x1;
}

__device__ inline float gumbel_from_bits(uint32_t bits) {
  // JAX uniform: bitcast((bits>>9)|0x3f800000) - 1, then *(1-tiny)+tiny, max(tiny, .)
  float fl = __uint_as_float((bits >> 9) | 0x3f800000u) - 1.0f;
  const float tiny = 1.17549435e-38f;
  float u = fmaxf(tiny, fl + tiny);
  return -logf(-logf(u));
}

__device__ inline float gumbel_at(uint32_t ka, uint32_t kb, uint32_t f) {
#if USE_PARTITIONABLE
  uint32_t o0, o1;
  tf2x32(ka, kb, 0u, f, &o0, &o1);   // counter = 64-bit flat index (hi=0, lo=f)
  return gumbel_from_bits(o0 ^ o1);  // 32-bit draw = XOR fold of both words
#else
  const uint32_t HALF = 16368u;      // (32*1023)/2
  uint32_t o0, o1;
  if (f < HALF) { tf2x32(ka, kb, f, f + HALF, &o0, &o1); return gumbel_from_bits(o0); }
  else          { tf2x32(ka, kb, f - HALF, f, &o0, &o1); return gumbel_from_bits(o1); }
#endif
}

// ---------------- CSR build ----------------
__global__ __launch_bounds__(256) void hist_kernel(const int* __restrict__ dst,
                                                   int* __restrict__ counts) {
  int i = blockIdx.x * 256 + threadIdx.x;
  atomicAdd(&counts[dst[i]], 1);
}

__global__ __launch_bounds__(1024) void scan_kernel(const int* __restrict__ counts,
                                                    int* __restrict__ rowptr,
                                                    int* __restrict__ cursor) {
  __shared__ int part[1024];
  int t = threadIdx.x;
  int base = t * 32;
  int local[32];
  int s = 0;
#pragma unroll
  for (int i = 0; i < 32; i++) { local[i] = s; s += counts[base + i]; }
  part[t] = s; __syncthreads();
  int own = s;
  for (int off = 1; off < 1024; off <<= 1) {
    int v = (t >= off) ? part[t - off] : 0;
    __syncthreads();
    part[t] += v;
    __syncthreads();
  }
  int excl = part[t] - own;
#pragma unroll
  for (int i = 0; i < 32; i++) {
    int v = excl + local[i];
    rowptr[base + i] = v;
    cursor[base + i] = v;
  }
  if (t == 1023) rowptr[NN] = part[1023];
}

__global__ __launch_bounds__(256) void scatter_kernel(const int* __restrict__ src,
                                                      const int* __restrict__ dst,
                                                      int* __restrict__ cursor,
                                                      int* __restrict__ col) {
  int i = blockIdx.x * 256 + threadIdx.x;
  int p = atomicAdd(&cursor[dst[i]], 1);
  col[p] = src[i];
}

// ---------------- fp32 GEMM: out[M,128] = in[M,128] @ W[128,128] (+ bias) ----------------
__global__ __launch_bounds__(256) void gemm128_kernel(const float* __restrict__ in,
                                                      const float* __restrict__ W,
                                                      const float* __restrict__ bias,
                                                      float* __restrict__ out, int hasBias) {
  __shared__ __align__(16) float ws[128 * 128];
  __shared__ __align__(16) float ins[64][132];
  int t = threadIdx.x;
  size_t row0 = (size_t)blockIdx.x * 64;
  {
    const float4* W4 = (const float4*)W;
    float4* ws4 = (float4*)ws;
#pragma unroll
    for (int i = 0; i < 16; i++) ws4[t + 256 * i] = W4[t + 256 * i];
    const float4* in4 = (const float4*)(in + row0 * 128);
#pragma unroll
    for (int i = 0; i < 8; i++) {
      int idx = t + 256 * i;
      int r = idx >> 5, c4 = idx & 31;
      float4 v = in4[(size_t)r * 32 + c4];
      *(float4*)&ins[r][c4 * 4] = v;
    }
  }
  __syncthreads();
  int cg = t & 15, rg = t >> 4;
  int c0 = cg * 8, r0 = rg * 4;
  float acc[4][8] = {};
#pragma unroll 8
  for (int k = 0; k < 128; k++) {
    float4 wA = *(const float4*)&ws[k * 128 + c0];
    float4 wB = *(const float4*)&ws[k * 128 + c0 + 4];
    float av[4];
    av[0] = ins[r0 + 0][k]; av[1] = ins[r0 + 1][k];
    av[2] = ins[r0 + 2][k]; av[3] = ins[r0 + 3][k];
#pragma unroll
    for (int i = 0; i < 4; i++) {
      acc[i][0] += av[i] * wA.x; acc[i][1] += av[i] * wA.y;
      acc[i][2] += av[i] * wA.z; acc[i][3] += av[i] * wA.w;
      acc[i][4] += av[i] * wB.x; acc[i][5] += av[i] * wB.y;
      acc[i][6] += av[i] * wB.z; acc[i][7] += av[i] * wB.w;
    }
  }
  float bb[8];
#pragma unroll
  for (int j = 0; j < 8; j++) bb[j] = hasBias ? bias[c0 + j] : 0.0f;
#pragma unroll
  for (int i = 0; i < 4; i++) {
    float* orow = out + (row0 + r0 + i) * 128 + c0;
    float4 o0, o1;
    o0.x = acc[i][0] + bb[0]; o0.y = acc[i][1] + bb[1];
    o0.z = acc[i][2] + bb[2]; o0.w = acc[i][3] + bb[3];
    o1.x = acc[i][4] + bb[4]; o1.y = acc[i][5] + bb[5];
    o1.z = acc[i][6] + bb[6]; o1.w = acc[i][7] + bb[7];
    *(float4*)orow = o0;
    *(float4*)(orow + 4) = o1;
  }
}

// ---------------- fused GAT edge kernel: one 32-lane group per dst node ----------------
// a_e = leaky(P[dst] + Q[src]) (P already includes +ba); segment softmax over dst;
// out[dst] = sum_e (exp(a_e - m) * h[src_e]) / (sum_e exp(a_e - m) + 1e-16)
__device__ inline float4 leaky4(float4 a) {
  a.x = a.x > 0.f ? a.x : NEG_SLOPE * a.x;
  a.y = a.y > 0.f ? a.y : NEG_SLOPE * a.y;
  a.z = a.z > 0.f ? a.z : NEG_SLOPE * a.z;
  a.w = a.w > 0.f ? a.w : NEG_SLOPE * a.w;
  return a;
}

__global__ __launch_bounds__(128) void gat_edge_kernel(const float* __restrict__ P,
                                                       const float* __restrict__ Q,
                                                       const float* __restrict__ H,
                                                       const int* __restrict__ rowptr,
                                                       const int* __restrict__ col,
                                                       float* __restrict__ out) {
  __shared__ float4 sa[4][CAPE][32];
  int g = threadIdx.x >> 5;
  int lane = threadIdx.x & 31;
  int dst = (blockIdx.x << 2) + g;
  int rs = rowptr[dst], re = rowptr[dst + 1];
  int deg = re - rs;
  int total = deg + 1;  // + self loop (src = dst), appended last like the reference
  float4 pd = ((const float4*)(P + (size_t)dst * DD))[lane];

  float4 m = make_float4(-INFINITY, -INFINITY, -INFINITY, -INFINITY);
  for (int e = 0; e < total; e++) {
    int s = (e == deg) ? dst : col[rs + e];
    float4 q = ((const float4*)(Q + (size_t)s * DD))[lane];
    float4 a = leaky4(make_float4(pd.x + q.x, pd.y + q.y, pd.z + q.z, pd.w + q.w));
    if (e < CAPE) sa[g][e][lane] = a;
    m.x = fmaxf(m.x, a.x); m.y = fmaxf(m.y, a.y);
    m.z = fmaxf(m.z, a.z); m.w = fmaxf(m.w, a.w);
  }
  float4 ssum = make_float4(0.f, 0.f, 0.f, 0.f);
  for (int e = 0; e < total; e++) {
    float4 a;
    if (e < CAPE) a = sa[g][e][lane];
    else {
      int s = (e == deg) ? dst : col[rs + e];
      float4 q = ((const float4*)(Q + (size_t)s * DD))[lane];
      a = leaky4(make_float4(pd.x + q.x, pd.y + q.y, pd.z + q.z, pd.w + q.w));
    }
    float4 ex = make_float4(expf(a.x - m.x), expf(a.y - m.y), expf(a.z - m.z), expf(a.w - m.w));
    if (e < CAPE) sa[g][e][lane] = ex;
    ssum.x += ex.x; ssum.y += ex.y; ssum.z += ex.z; ssum.w += ex.w;
  }
  float4 inv = make_float4(1.f / (ssum.x + 1e-16f), 1.f / (ssum.y + 1e-16f),
                           1.f / (ssum.z + 1e-16f), 1.f / (ssum.w + 1e-16f));
  float4 acc = make_float4(0.f, 0.f, 0.f, 0.f);
  for (int e = 0; e < total; e++) {
    int s = (e == deg) ? dst : col[rs + e];
    float4 ex;
    if (e < CAPE) ex = sa[g][e][lane];
    else {
      float4 q = ((const float4*)(Q + (size_t)s * DD))[lane];
      float4 a = leaky4(make_float4(pd.x + q.x, pd.y + q.y, pd.z + q.z, pd.w + q.w));
      ex = make_float4(expf(a.x - m.x), expf(a.y - m.y), expf(a.z - m.z), expf(a.w - m.w));
    }
    float4 hv = ((const float4*)(H + (size_t)s * DD))[lane];
    acc.x += ex.x * hv.x; acc.y += ex.y * hv.y;
    acc.z += ex.z * hv.z; acc.w += ex.w * hv.w;
  }
  float4 o = make_float4(acc.x * inv.x, acc.y * inv.y, acc.z * inv.z, acc.w * inv.w);
  ((float4*)(out + (size_t)dst * DD))[lane] = o;
}

// ---------------- final stage ----------------
__global__ __launch_bounds__(256) void logits_kernel(const float* __restrict__ X,
                                                     const float* __restrict__ Wp,
                                                     const float* __restrict__ bp,
                                                     float* __restrict__ logits) {
  int w = threadIdx.x >> 6, lane = threadIdx.x & 63;
  int n = blockIdx.x * 4 + w;
  const float* xr = X + (size_t)n * DD;
  float p = xr[lane] * Wp[lane] + xr[lane + 64] * Wp[lane + 64];
  for (int off = 32; off > 0; off >>= 1) p += __shfl_down(p, off);
  if (lane == 0) logits[n] = p + bp[0];
}

__global__ __launch_bounds__(1024) void hmean_kernel(const float* __restrict__ X,
                                                     float* __restrict__ out) {
  int b = blockIdx.x;
  int t = threadIdx.x;
  int c = t & 127, part = t >> 7;  // 8 parts x 128 channels
  float acc = 0.f;
  for (int i = part; i < NPG; i += 8)
    acc += X[((size_t)b * NPG + i) * DD + c];
  __shared__ float red[1024];
  red[t] = acc; __syncthreads();
  if (part == 0) {
    float s = 0.f;
#pragma unroll
    for (int p = 0; p < 8; p++) s += red[p * 128 + c];
    out[b * DD + c] = s * (1.0f / (float)NPG);
  }
}

__global__ __launch_bounds__(256) void sample1_kernel(const float* __restrict__ logits,
                                                      uint32_t ka, uint32_t kb,
                                                      int* __restrict__ idx1_ws,
                                                      float* __restrict__ p1_ws,
                                                      float* __restrict__ out) {
  int b = blockIdx.x, t = threadIdx.x;
  __shared__ float sV[256]; __shared__ int sJ[256]; __shared__ float sM[256];
  float bestV = -INFINITY; int bestJ = 1 << 30; float maxL = -INFINITY;
  for (int j = 1 + t; j < NPG; j += 256) {
    float l = logits[(size_t)b * NPG + j];
    maxL = fmaxf(maxL, l);
    float v = l + gumbel_at(ka, kb, (uint32_t)(b * 1023 + j - 1));
    if (v > bestV) { bestV = v; bestJ = j; }
  }
  sV[t] = bestV; sJ[t] = bestJ; sM[t] = maxL; __syncthreads();
  for (int off = 128; off > 0; off >>= 1) {
    if (t < off) {
      if (sV[t + off] > sV[t] || (sV[t + off] == sV[t] && sJ[t + off] < sJ[t])) {
        sV[t] = sV[t + off]; sJ[t] = sJ[t + off];
      }
      sM[t] = fmaxf(sM[t], sM[t + off]);
    }
    __syncthreads();
  }
  float M = sM[0]; int idx = sJ[0];
  __syncthreads();
  float ps = 0.f;
  for (int j = 1 + t; j < NPG; j += 256)
    ps += expf(logits[(size_t)b * NPG + j] - M);
  sV[t] = ps; __syncthreads();
  for (int off = 128; off > 0; off >>= 1) {
    if (t < off) sV[t] += sV[t + off];
    __syncthreads();
  }
  if (t == 0) {
    float S = sV[0];
    float p1 = expf(logits[(size_t)b * NPG + idx] - M) / S;
    idx1_ws[b] = idx;
    p1_ws[b] = p1;
    out[NB * DD + b] = (float)idx;  // index1 output
  }
}

__global__ __launch_bounds__(128) void zk_kernel(const float* __restrict__ X,
                                                 const float* __restrict__ Wa1,
                                                 const int* __restrict__ idx1,
                                                 float* __restrict__ Z) {
  int b = blockIdx.x, c = threadIdx.x;
  __shared__ float xs[128];
  int node = b * NPG + idx1[b];
  xs[c] = X[(size_t)node * DD + c];
  __syncthreads();
  float acc = 0.f;
#pragma unroll 8
  for (int k = 0; k < 128; k++) acc += xs[k] * Wa1[k * 128 + c];
  Z[b * DD + c] = acc;
}

__global__ __launch_bounds__(256) void u_kernel(const float* __restrict__ Y,
                                                const float* __restrict__ Z,
                                                const float* __restrict__ vt,
                                                const int* __restrict__ idx1,
                                                float* __restrict__ u) {
  int w = threadIdx.x >> 6, lane = threadIdx.x & 63;
  int n = blockIdx.x * 4 + w;
  int b = n >> 10;
  float t0 = tanhf(Z[b * DD + lane] + Y[(size_t)n * DD + lane]) * vt[lane];
  float t1 = tanhf(Z[b * DD + lane + 64] + Y[(size_t)n * DD + lane + 64]) * vt[lane + 64];
  float p = t0 + t1;
  for (int off = 32; off > 0; off >>= 1) p += __shfl_down(p, off);
  if (lane == 0) u[n] = ((n & (NPG - 1)) == idx1[b]) ? -INFINITY : p;
}

__global__ __launch_bounds__(256) void sample2_kernel(const float* __restrict__ u,
                                                      uint32_t ka, uint32_t kb,
                                                      const float* __restrict__ p1_ws,
                                                      float* __restrict__ out) {
  int b = blockIdx.x, t = threadIdx.x;
  __shared__ float sV[256]; __shared__ int sJ[256]; __shared__ float sM[256];
  float bestV = -INFINITY; int bestJ = 1 << 30; float maxL = -INFINITY;
  for (int j = 1 + t; j < NPG; j += 256) {
    float l = u[(size_t)b * NPG + j];
    maxL = fmaxf(maxL, l);
    float v = l + gumbel_at(ka, kb, (uint32_t)(b * 1023 + j - 1));  // -inf stays -inf
    if (v > bestV) { bestV = v; bestJ = j; }
  }
  sV[t] = bestV; sJ[t] = bestJ; sM[t] = maxL; __syncthreads();
  for (int off = 128; off > 0; off >>= 1) {
    if (t < off) {
      if (sV[t + off] > sV[t] || (sV[t + off] == sV[t] && sJ[t + off] < sJ[t])) {
        sV[t] = sV[t + off]; sJ[t] = sJ[t + off];
      }
      sM[t] = fmaxf(sM[t], sM[t + off]);
    }
    __syncthreads();
  }
  float M = sM[0]; int idx = sJ[0];
  __syncthreads();
  float ps = 0.f;
  for (int j = 1 + t; j < NPG; j += 256) {
    float l = u[(size_t)b * NPG + j];
    ps += expf(l - M);  // exp(-inf - M) = 0
  }
  sV[t] = ps; __syncthreads();
  for (int off = 128; off > 0; off >>= 1) {
    if (t < off) sV[t] += sV[t + off];
    __syncthreads();
  }
  if (t == 0) {
    float S = sV[0];
    float p2 = expf(u[(size_t)b * NPG + idx] - M) / S;
    out[NB * DD + NB + b] = (float)idx;                 // index2
    out[NB * DD + 2 * NB + b] = logf(p1_ws[b] + p2);    // log_probs
  }
}

// ---------------- host launcher ----------------
extern "C" void kernel_launch(void* const* d_in, const int* in_sizes, int n_in,
                              void* d_out, int out_size, void* d_ws, size_t ws_size,
                              hipStream_t stream) {
  const float* x  = (const float*)d_in[0];
  const int* eN   = (const int*)d_in[1];
  const int* eR0  = (const int*)d_in[2];
  const int* eR1  = (const int*)d_in[3];
  const float* W0l = (const float*)d_in[4];  const float* b0l = (const float*)d_in[5];
  const float* W0a = (const float*)d_in[6];  const float* b0a = (const float*)d_in[7];
  const float* W1l = (const float*)d_in[8];  const float* b1l = (const float*)d_in[9];
  const float* W1a = (const float*)d_in[10]; const float* b1a = (const float*)d_in[11];
  const float* W2l = (const float*)d_in[12]; const float* b2l = (const float*)d_in[13];
  const float* W2a = (const float*)d_in[14]; const float* b2a = (const float*)d_in[15];
  const float* Wp  = (const float*)d_in[16]; const float* bp  = (const float*)d_in[17];
  const float* Wa1 = (const float*)d_in[18]; const float* Wa2 = (const float*)d_in[19];
  const float* vt  = (const float*)d_in[20];
  float* out = (float*)d_out;

  char* wsb = (char*)d_ws;
  size_t off = 0;
  auto take = [&](size_t bytes) -> char* {
    char* p = wsb + off;
    off += (bytes + 255) & ~(size_t)255;
    return p;
  };
  int* rowptrAll = (int*)take((size_t)3 * (NN + 1) * sizeof(int));
  int* counts    = (int*)take((size_t)NN * sizeof(int));
  int* cursor    = (int*)take((size_t)NN * sizeof(int));
  int* colAll    = (int*)take((size_t)3 * EE * sizeof(int));
  float* bufA    = (float*)take((size_t)NN * DD * 4);
  float* bufB    = (float*)take((size_t)NN * DD * 4);
  float* hb      = (float*)take((size_t)NN * DD * 4);
  float* Pb      = (float*)take((size_t)NN * DD * 4);
  float* Qb      = (float*)take((size_t)NN * DD * 4);
  float* logits  = (float*)take((size_t)NN * 4);
  float* ub      = (float*)take((size_t)NN * 4);
  float* Zb      = (float*)take((size_t)NB * DD * 4);
  int* idx1b     = (int*)take(NB * 4);
  float* p1b     = (float*)take(NB * 4);

  // keys: jax.random.key(42) = (0,42); k1,k2 = split(key)
  uint32_t k1a, k1b, k2a, k2b;
#if USE_PARTITIONABLE
  {  // fold-like split: key_i = full cipher output at counter (0, i)
    uint32_t o0, o1;
    tf2x32(0u, 42u, 0u, 0u, &o0, &o1); k1a = o0; k1b = o1;
    tf2x32(0u, 42u, 0u, 1u, &o0, &o1); k2a = o0; k2b = o1;
  }
#else
  {  // legacy split: threefry_2x32(key, iota(4)) -> halves [0,1],[2,3] -> pairs (0,2),(1,3)
    uint32_t a0, b0, a1, b1;
    tf2x32(0u, 42u, 0u, 2u, &a0, &b0);
    tf2x32(0u, 42u, 1u, 3u, &a1, &b1);
    k1a = a0; k1b = a1; k2a = b0; k2b = b1;
  }
#endif

  // ---- CSR for the 3 edge sets (dst = row 1 of edge_index) ----
  const int* esets[3] = {eN, eR0, eR1};
  for (int s = 0; s < 3; s++) {
    int* rp = rowptrAll + s * (NN + 1);
    int* cl = colAll + (size_t)s * EE;
    hipMemsetAsync(counts, 0, NN * sizeof(int), stream);
    hist_kernel<<<EE / 256, 256, 0, stream>>>(esets[s] + EE, counts);
    scan_kernel<<<1, 1024, 0, stream>>>(counts, rp, cursor);
    scatter_kernel<<<EE / 256, 256, 0, stream>>>(esets[s], esets[s] + EE, cursor, cl);
  }

  // ---- 5 GAT layers; edge-set per layer: n, r1, r0, r1, r0 -> sets {0,2,1,2,1} ----
  struct Layer { const float* in; float* o; const float *Wl, *bl, *Wa, *ba; int set; };
  Layer Ls[5] = {
      {x,    bufA, W0l, b0l, W0a, b0a, 0},
      {bufA, bufB, W1l, b1l, W1a, b1a, 2},
      {bufB, bufA, W2l, b2l, W2a, b2a, 1},
      {bufA, bufB, W1l, b1l, W1a, b1a, 2},
      {bufB, bufA, W2l, b2l, W2a, b2a, 1},
  };
  for (int L = 0; L < 5; L++) {
    gemm128_kernel<<<NN / 64, 256, 0, stream>>>(Ls[L].in, Ls[L].Wl, Ls[L].bl, hb, 1);
    // P = h @ Wa[:128] + ba  (dst term, bias folded here); Q = h @ Wa[128:]  (src term)
    gemm128_kernel<<<NN / 64, 256, 0, stream>>>(hb, Ls[L].Wa, Ls[L].ba, Pb, 1);
    gemm128_kernel<<<NN / 64, 256, 0, stream>>>(hb, Ls[L].Wa + 128 * 128, nullptr, Qb, 0);
    gat_edge_kernel<<<NN / 4, 128, 0, stream>>>(
        Pb, Qb, hb, rowptrAll + Ls[L].set * (NN + 1),
        colAll + (size_t)Ls[L].set * EE, Ls[L].o);
  }
  const float* X = bufA;  // g4

  // ---- heads ----
  gemm128_kernel<<<NN / 64, 256, 0, stream>>>(X, Wa2, nullptr, Pb, 0);  // Y = X @ Wa2
  logits_kernel<<<NN / 4, 256, 0, stream>>>(X, Wp, bp, logits);
  hmean_kernel<<<NB, 1024, 0, stream>>>(X, out);
  sample1_kernel<<<NB, 256, 0, stream>>>(logits, k1a, k1b, idx1b, p1b, out);
  zk_kernel<<<NB, 128, 0, stream>>>(X, Wa1, idx1b, Zb);
  u_kernel<<<NN / 4, 256, 0, stream>>>(Pb, Zb, vt, idx1b, ub);
  sample2_kernel<<<NB, 256, 0, stream>>>(ub, k2a, k2b, p1b, out);
}

// Round 4
// 902.732 us; speedup vs baseline: 1.5221x; 1.5221x over previous
//
#include <hip/hip_runtime.h>
#include <stdint.h>
#include <math.h>

#define NN 32768      // total nodes
#define EE 262144     // edges per edge set (before self loops)
#define DD 128
#define NPG 1024
#define NB 32
#define NEG_SLOPE 0.2f
#define USE_PARTITIONABLE 1

// ---------------- threefry2x32 (exact JAX algorithm) ----------------
__host__ __device__ inline void tf2x32(uint32_t k0, uint32_t k1, uint32_t c0, uint32_t c1,
                                       uint32_t* o0, uint32_t* o1) {
  uint32_t ks2 = k0 ^ k1 ^ 0x1BD11BDAu;
  uint32_t x0 = c0 + k0;
  uint32_t x1 = c1 + k1;
#define TFR(r) { x0 += x1; x1 = (x1 << (r)) | (x1 >> (32 - (r))); x1 ^= x0; }
  TFR(13) TFR(15) TFR(26) TFR(6)
  x0 += k1; x1 += ks2 + 1u;
  TFR(17) TFR(29) TFR(16) TFR(24)
  x0 += ks2; x1 += k0 + 2u;
  TFR(13) TFR(15) TFR(26) TFR(6)
  x0 += k0; x1 += k1 + 3u;
  TFR(17) TFR(29) TFR(16) TFR(24)
  x0 += k1; x1 += ks2 + 4u;
  TFR(13) TFR(15) TFR(26) TFR(6)
  x0 += ks2; x1 += k0 + 5u;
#undef TFR
  *o0 = x0; *o1 = x1;
}

__device__ inline float gumbel_from_bits(uint32_t bits) {
  // JAX uniform: bitcast((bits>>9)|0x3f800000) - 1, then *(1-tiny)+tiny, max(tiny, .)
  float fl = __uint_as_float((bits >> 9) | 0x3f800000u) - 1.0f;
  const float tiny = 1.17549435e-38f;
  float u = fmaxf(tiny, fl + tiny);
  return -logf(-logf(u));
}

__device__ inline float gumbel_at(uint32_t ka, uint32_t kb, uint32_t f) {
#if USE_PARTITIONABLE
  uint32_t o0, o1;
  tf2x32(ka, kb, 0u, f, &o0, &o1);   // counter = 64-bit flat index (hi=0, lo=f)
  return gumbel_from_bits(o0 ^ o1);  // 32-bit draw = XOR fold of both words
#else
  const uint32_t HALF = 16368u;      // (32*1023)/2
  uint32_t o0, o1;
  if (f < HALF) { tf2x32(ka, kb, f, f + HALF, &o0, &o1); return gumbel_from_bits(o0); }
  else          { tf2x32(ka, kb, f - HALF, f, &o0, &o1); return gumbel_from_bits(o1); }
#endif
}

// ---------------- CSR build ----------------
__global__ __launch_bounds__(256) void hist_kernel(const int* __restrict__ dst,
                                                   int* __restrict__ counts) {
  int i = blockIdx.x * 256 + threadIdx.x;
  atomicAdd(&counts[dst[i]], 1);
}

__global__ __launch_bounds__(1024) void scan_kernel(const int* __restrict__ counts,
                                                    int* __restrict__ rowptr,
                                                    int* __restrict__ cursor) {
  __shared__ int part[1024];
  int t = threadIdx.x;
  int base = t * 32;
  int local[32];
  {  // vectorized int4 loads of the 32 counts
    const int4* c4 = (const int4*)(counts + base);
    int s = 0;
#pragma unroll
    for (int v = 0; v < 8; v++) {
      int4 cc = c4[v];
      local[v * 4 + 0] = s; s += cc.x;
      local[v * 4 + 1] = s; s += cc.y;
      local[v * 4 + 2] = s; s += cc.z;
      local[v * 4 + 3] = s; s += cc.w;
    }
    part[t] = s;
  }
  __syncthreads();
  int own = part[t];
  int run = own;
  for (int off = 1; off < 1024; off <<= 1) {
    int v = (t >= off) ? part[t - off] : 0;
    __syncthreads();
    part[t] += v;
    __syncthreads();
  }
  (void)run;
  int excl = part[t] - own;
  {
    int4* rp4 = (int4*)(rowptr + base);
    int4* cu4 = (int4*)(cursor + base);
#pragma unroll
    for (int v = 0; v < 8; v++) {
      int4 w;
      w.x = excl + local[v * 4 + 0];
      w.y = excl + local[v * 4 + 1];
      w.z = excl + local[v * 4 + 2];
      w.w = excl + local[v * 4 + 3];
      rp4[v] = w;
      cu4[v] = w;
    }
  }
  if (t == 1023) rowptr[NN] = part[1023];
}

__global__ __launch_bounds__(256) void scatter_kernel(const int* __restrict__ src,
                                                      const int* __restrict__ dst,
                                                      int* __restrict__ cursor,
                                                      int* __restrict__ col) {
  int i = blockIdx.x * 256 + threadIdx.x;
  int p = atomicAdd(&cursor[dst[i]], 1);
  col[p] = src[i];
}

// ---------------- fp32 GEMM: out[M,128] = in[M,128] @ W[128,128] (+ bias) ----------------
__global__ __launch_bounds__(256) void gemm128_kernel(const float* __restrict__ in,
                                                      const float* __restrict__ W,
                                                      const float* __restrict__ bias,
                                                      float* __restrict__ out, int hasBias) {
  __shared__ __align__(16) float ws[128 * 128];
  __shared__ __align__(16) float ins[64][132];
  int t = threadIdx.x;
  size_t row0 = (size_t)blockIdx.x * 64;
  {
    const float4* W4 = (const float4*)W;
    float4* ws4 = (float4*)ws;
#pragma unroll
    for (int i = 0; i < 16; i++) ws4[t + 256 * i] = W4[t + 256 * i];
    const float4* in4 = (const float4*)(in + row0 * 128);
#pragma unroll
    for (int i = 0; i < 8; i++) {
      int idx = t + 256 * i;
      int r = idx >> 5, c4 = idx & 31;
      float4 v = in4[(size_t)r * 32 + c4];
      *(float4*)&ins[r][c4 * 4] = v;
    }
  }
  __syncthreads();
  int cg = t & 15, rg = t >> 4;
  int c0 = cg * 8, r0 = rg * 4;
  float acc[4][8] = {};
#pragma unroll 8
  for (int k = 0; k < 128; k++) {
    float4 wA = *(const float4*)&ws[k * 128 + c0];
    float4 wB = *(const float4*)&ws[k * 128 + c0 + 4];
    float av[4];
    av[0] = ins[r0 + 0][k]; av[1] = ins[r0 + 1][k];
    av[2] = ins[r0 + 2][k]; av[3] = ins[r0 + 3][k];
#pragma unroll
    for (int i = 0; i < 4; i++) {
      acc[i][0] += av[i] * wA.x; acc[i][1] += av[i] * wA.y;
      acc[i][2] += av[i] * wA.z; acc[i][3] += av[i] * wA.w;
      acc[i][4] += av[i] * wB.x; acc[i][5] += av[i] * wB.y;
      acc[i][6] += av[i] * wB.z; acc[i][7] += av[i] * wB.w;
    }
  }
  float bb[8];
#pragma unroll
  for (int j = 0; j < 8; j++) bb[j] = hasBias ? bias[c0 + j] : 0.0f;
#pragma unroll
  for (int i = 0; i < 4; i++) {
    float* orow = out + (row0 + r0 + i) * 128 + c0;
    float4 o0, o1;
    o0.x = acc[i][0] + bb[0]; o0.y = acc[i][1] + bb[1];
    o0.z = acc[i][2] + bb[2]; o0.w = acc[i][3] + bb[3];
    o1.x = acc[i][4] + bb[4]; o1.y = acc[i][5] + bb[5];
    o1.z = acc[i][6] + bb[6]; o1.w = acc[i][7] + bb[7];
    *(float4*)orow = o0;
    *(float4*)(orow + 4) = o1;
  }
}

// ---------------- fused GAT edge kernel: one 64-lane WAVE per dst node ----------------
// One-pass online softmax: a_e = leaky(P[dst]+Q[src]); running (m, s, acc) with
// rescale; out[dst] = acc / (s + 1e-16). No LDS -> high occupancy. Neighbor
// indices preloaded into lanes, broadcast via readlane -> SGPR row base.
__device__ inline float lk1(float v) { return v > 0.f ? v : NEG_SLOPE * v; }

__global__ __launch_bounds__(256, 4) void gat_edge_kernel(const float* __restrict__ P,
                                                          const float* __restrict__ Q,
                                                          const float* __restrict__ H,
                                                          const int* __restrict__ rowptr,
                                                          const int* __restrict__ col,
                                                          float* __restrict__ out) {
  int wv = threadIdx.x >> 6;
  int lane = threadIdx.x & 63;
  int dst = (blockIdx.x << 2) + wv;
  int rs = __builtin_amdgcn_readfirstlane(rowptr[dst]);
  int re = __builtin_amdgcn_readfirstlane(rowptr[dst + 1]);
  int deg = re - rs;
  int total = deg + 1;  // + self loop, appended last like the reference
  float2 pd = ((const float2*)(P + (size_t)dst * DD))[lane];

  float mx = -INFINITY, my = -INFINITY;
  float sx = 0.f, sy = 0.f;
  float cx = 0.f, cy = 0.f;

  for (int base = 0; base < total; base += 64) {
    int cnt = min(64, total - base);
    int e = base + lane;
    int myidx = (e < deg) ? col[rs + e] : dst;  // e==deg -> self loop
    int i = 0;
    for (; i + 4 <= cnt; i += 4) {
      int iu = __builtin_amdgcn_readfirstlane(i);
      int n0 = __builtin_amdgcn_readlane(myidx, iu);
      int n1 = __builtin_amdgcn_readlane(myidx, iu + 1);
      int n2 = __builtin_amdgcn_readlane(myidx, iu + 2);
      int n3 = __builtin_amdgcn_readlane(myidx, iu + 3);
      float2 q0 = ((const float2*)(Q + (size_t)n0 * DD))[lane];
      float2 q1 = ((const float2*)(Q + (size_t)n1 * DD))[lane];
      float2 q2 = ((const float2*)(Q + (size_t)n2 * DD))[lane];
      float2 q3 = ((const float2*)(Q + (size_t)n3 * DD))[lane];
      float2 h0 = ((const float2*)(H + (size_t)n0 * DD))[lane];
      float2 h1 = ((const float2*)(H + (size_t)n1 * DD))[lane];
      float2 h2 = ((const float2*)(H + (size_t)n2 * DD))[lane];
      float2 h3 = ((const float2*)(H + (size_t)n3 * DD))[lane];
      float a0x = lk1(pd.x + q0.x), a0y = lk1(pd.y + q0.y);
      float a1x = lk1(pd.x + q1.x), a1y = lk1(pd.y + q1.y);
      float a2x = lk1(pd.x + q2.x), a2y = lk1(pd.y + q2.y);
      float a3x = lk1(pd.x + q3.x), a3y = lk1(pd.y + q3.y);
      float nmx = fmaxf(fmaxf(mx, fmaxf(a0x, a1x)), fmaxf(a2x, a3x));
      float nmy = fmaxf(fmaxf(my, fmaxf(a0y, a1y)), fmaxf(a2y, a3y));
      float scx = expf(mx - nmx), scy = expf(my - nmy);
      float e0x = expf(a0x - nmx), e1x = expf(a1x - nmx);
      float e2x = expf(a2x - nmx), e3x = expf(a3x - nmx);
      float e0y = expf(a0y - nmy), e1y = expf(a1y - nmy);
      float e2y = expf(a2y - nmy), e3y = expf(a3y - nmy);
      sx = sx * scx + ((e0x + e1x) + (e2x + e3x));
      sy = sy * scy + ((e0y + e1y) + (e2y + e3y));
      cx = cx * scx + ((e0x * h0.x + e1x * h1.x) + (e2x * h2.x + e3x * h3.x));
      cy = cy * scy + ((e0y * h0.y + e1y * h1.y) + (e2y * h2.y + e3y * h3.y));
      mx = nmx; my = nmy;
    }
    for (; i < cnt; i++) {
      int iu = __builtin_amdgcn_readfirstlane(i);
      int n0 = __builtin_amdgcn_readlane(myidx, iu);
      float2 q0 = ((const float2*)(Q + (size_t)n0 * DD))[lane];
      float2 h0 = ((const float2*)(H + (size_t)n0 * DD))[lane];
      float a0x = lk1(pd.x + q0.x), a0y = lk1(pd.y + q0.y);
      float nmx = fmaxf(mx, a0x), nmy = fmaxf(my, a0y);
      float scx = expf(mx - nmx), scy = expf(my - nmy);
      float e0x = expf(a0x - nmx), e0y = expf(a0y - nmy);
      sx = sx * scx + e0x;
      sy = sy * scy + e0y;
      cx = cx * scx + e0x * h0.x;
      cy = cy * scy + e0y * h0.y;
      mx = nmx; my = nmy;
    }
  }
  float2 o = make_float2(cx / (sx + 1e-16f), cy / (sy + 1e-16f));
  ((float2*)(out + (size_t)dst * DD))[lane] = o;
}

// ---------------- final stage ----------------
__global__ __launch_bounds__(256) void logits_kernel(const float* __restrict__ X,
                                                     const float* __restrict__ Wp,
                                                     const float* __restrict__ bp,
                                                     float* __restrict__ logits) {
  int w = threadIdx.x >> 6, lane = threadIdx.x & 63;
  int n = blockIdx.x * 4 + w;
  const float* xr = X + (size_t)n * DD;
  float p = xr[lane] * Wp[lane] + xr[lane + 64] * Wp[lane + 64];
  for (int off = 32; off > 0; off >>= 1) p += __shfl_down(p, off);
  if (lane == 0) logits[n] = p + bp[0];
}

__global__ __launch_bounds__(1024) void hmean_kernel(const float* __restrict__ X,
                                                     float* __restrict__ out) {
  int b = blockIdx.x;
  int t = threadIdx.x;
  int c = t & 127, part = t >> 7;  // 8 parts x 128 channels
  float acc = 0.f;
  for (int i = part; i < NPG; i += 8)
    acc += X[((size_t)b * NPG + i) * DD + c];
  __shared__ float red[1024];
  red[t] = acc; __syncthreads();
  if (part == 0) {
    float s = 0.f;
#pragma unroll
    for (int p = 0; p < 8; p++) s += red[p * 128 + c];
    out[b * DD + c] = s * (1.0f / (float)NPG);
  }
}

__global__ __launch_bounds__(256) void sample1_kernel(const float* __restrict__ logits,
                                                      uint32_t ka, uint32_t kb,
                                                      int* __restrict__ idx1_ws,
                                                      float* __restrict__ p1_ws,
                                                      float* __restrict__ out) {
  int b = blockIdx.x, t = threadIdx.x;
  __shared__ float sV[256]; __shared__ int sJ[256]; __shared__ float sM[256];
  float bestV = -INFINITY; int bestJ = 1 << 30; float maxL = -INFINITY;
  for (int j = 1 + t; j < NPG; j += 256) {
    float l = logits[(size_t)b * NPG + j];
    maxL = fmaxf(maxL, l);
    float v = l + gumbel_at(ka, kb, (uint32_t)(b * 1023 + j - 1));
    if (v > bestV) { bestV = v; bestJ = j; }
  }
  sV[t] = bestV; sJ[t] = bestJ; sM[t] = maxL; __syncthreads();
  for (int off = 128; off > 0; off >>= 1) {
    if (t < off) {
      if (sV[t + off] > sV[t] || (sV[t + off] == sV[t] && sJ[t + off] < sJ[t])) {
        sV[t] = sV[t + off]; sJ[t] = sJ[t + off];
      }
      sM[t] = fmaxf(sM[t], sM[t + off]);
    }
    __syncthreads();
  }
  float M = sM[0]; int idx = sJ[0];
  __syncthreads();
  float ps = 0.f;
  for (int j = 1 + t; j < NPG; j += 256)
    ps += expf(logits[(size_t)b * NPG + j] - M);
  sV[t] = ps; __syncthreads();
  for (int off = 128; off > 0; off >>= 1) {
    if (t < off) sV[t] += sV[t + off];
    __syncthreads();
  }
  if (t == 0) {
    float S = sV[0];
    float p1 = expf(logits[(size_t)b * NPG + idx] - M) / S;
    idx1_ws[b] = idx;
    p1_ws[b] = p1;
    out[NB * DD + b] = (float)idx;  // index1 output
  }
}

__global__ __launch_bounds__(128) void zk_kernel(const float* __restrict__ X,
                                                 const float* __restrict__ Wa1,
                                                 const int* __restrict__ idx1,
                                                 float* __restrict__ Z) {
  int b = blockIdx.x, c = threadIdx.x;
  __shared__ float xs[128];
  int node = b * NPG + idx1[b];
  xs[c] = X[(size_t)node * DD + c];
  __syncthreads();
  float acc = 0.f;
#pragma unroll 8
  for (int k = 0; k < 128; k++) acc += xs[k] * Wa1[k * 128 + c];
  Z[b * DD + c] = acc;
}

__global__ __launch_bounds__(256) void u_kernel(const float* __restrict__ Y,
                                                const float* __restrict__ Z,
                                                const float* __restrict__ vt,
                                                const int* __restrict__ idx1,
                                                float* __restrict__ u) {
  int w = threadIdx.x >> 6, lane = threadIdx.x & 63;
  int n = blockIdx.x * 4 + w;
  int b = n >> 10;
  float t0 = tanhf(Z[b * DD + lane] + Y[(size_t)n * DD + lane]) * vt[lane];
  float t1 = tanhf(Z[b * DD + lane + 64] + Y[(size_t)n * DD + lane + 64]) * vt[lane + 64];
  float p = t0 + t1;
  for (int off = 32; off > 0; off >>= 1) p += __shfl_down(p, off);
  if (lane == 0) u[n] = ((n & (NPG - 1)) == idx1[b]) ? -INFINITY : p;
}

__global__ __launch_bounds__(256) void sample2_kernel(const float* __restrict__ u,
                                                      uint32_t ka, uint32_t kb,
                                                      const float* __restrict__ p1_ws,
                                                      float* __restrict__ out) {
  int b = blockIdx.x, t = threadIdx.x;
  __shared__ float sV[256]; __shared__ int sJ[256]; __shared__ float sM[256];
  float bestV = -INFINITY; int bestJ = 1 << 30; float maxL = -INFINITY;
  for (int j = 1 + t; j < NPG; j += 256) {
    float l = u[(size_t)b * NPG + j];
    maxL = fmaxf(maxL, l);
    float v = l + gumbel_at(ka, kb, (uint32_t)(b * 1023 + j - 1));  // -inf stays -inf
    if (v > bestV) { bestV = v; bestJ = j; }
  }
  sV[t] = bestV; sJ[t] = bestJ; sM[t] = maxL; __syncthreads();
  for (int off = 128; off > 0; off >>= 1) {
    if (t < off) {
      if (sV[t + off] > sV[t] || (sV[t + off] == sV[t] && sJ[t + off] < sJ[t])) {
        sV[t] = sV[t + off]; sJ[t] = sJ[t + off];
      }
      sM[t] = fmaxf(sM[t], sM[t + off]);
    }
    __syncthreads();
  }
  float M = sM[0]; int idx = sJ[0];
  __syncthreads();
  float ps = 0.f;
  for (int j = 1 + t; j < NPG; j += 256) {
    float l = u[(size_t)b * NPG + j];
    ps += expf(l - M);  // exp(-inf - M) = 0
  }
  sV[t] = ps; __syncthreads();
  for (int off = 128; off > 0; off >>= 1) {
    if (t < off) sV[t] += sV[t + off];
    __syncthreads();
  }
  if (t == 0) {
    float S = sV[0];
    float p2 = expf(u[(size_t)b * NPG + idx] - M) / S;
    out[NB * DD + NB + b] = (float)idx;                 // index2
    out[NB * DD + 2 * NB + b] = logf(p1_ws[b] + p2);    // log_probs
  }
}

// ---------------- host launcher ----------------
extern "C" void kernel_launch(void* const* d_in, const int* in_sizes, int n_in,
                              void* d_out, int out_size, void* d_ws, size_t ws_size,
                              hipStream_t stream) {
  const float* x  = (const float*)d_in[0];
  const int* eN   = (const int*)d_in[1];
  const int* eR0  = (const int*)d_in[2];
  const int* eR1  = (const int*)d_in[3];
  const float* W0l = (const float*)d_in[4];  const float* b0l = (const float*)d_in[5];
  const float* W0a = (const float*)d_in[6];  const float* b0a = (const float*)d_in[7];
  const float* W1l = (const float*)d_in[8];  const float* b1l = (const float*)d_in[9];
  const float* W1a = (const float*)d_in[10]; const float* b1a = (const float*)d_in[11];
  const float* W2l = (const float*)d_in[12]; const float* b2l = (const float*)d_in[13];
  const float* W2a = (const float*)d_in[14]; const float* b2a = (const float*)d_in[15];
  const float* Wp  = (const float*)d_in[16]; const float* bp  = (const float*)d_in[17];
  const float* Wa1 = (const float*)d_in[18]; const float* Wa2 = (const float*)d_in[19];
  const float* vt  = (const float*)d_in[20];
  float* out = (float*)d_out;

  char* wsb = (char*)d_ws;
  size_t off = 0;
  auto take = [&](size_t bytes) -> char* {
    char* p = wsb + off;
    off += (bytes + 255) & ~(size_t)255;
    return p;
  };
  int* rowptrAll = (int*)take((size_t)3 * (NN + 1) * sizeof(int));
  int* counts    = (int*)take((size_t)NN * sizeof(int));
  int* cursor    = (int*)take((size_t)NN * sizeof(int));
  int* colAll    = (int*)take((size_t)3 * EE * sizeof(int));
  float* bufA    = (float*)take((size_t)NN * DD * 4);
  float* bufB    = (float*)take((size_t)NN * DD * 4);
  float* hb      = (float*)take((size_t)NN * DD * 4);
  float* Pb      = (float*)take((size_t)NN * DD * 4);
  float* Qb      = (float*)take((size_t)NN * DD * 4);
  float* logits  = (float*)take((size_t)NN * 4);
  float* ub      = (float*)take((size_t)NN * 4);
  float* Zb      = (float*)take((size_t)NB * DD * 4);
  int* idx1b     = (int*)take(NB * 4);
  float* p1b     = (float*)take(NB * 4);

  // keys: jax.random.key(42) = (0,42); k1,k2 = split(key)
  uint32_t k1a, k1b, k2a, k2b;
#if USE_PARTITIONABLE
  {  // fold-like split: key_i = full cipher output at counter (0, i)
    uint32_t o0, o1;
    tf2x32(0u, 42u, 0u, 0u, &o0, &o1); k1a = o0; k1b = o1;
    tf2x32(0u, 42u, 0u, 1u, &o0, &o1); k2a = o0; k2b = o1;
  }
#else
  {  // legacy split
    uint32_t a0, b0, a1, b1;
    tf2x32(0u, 42u, 0u, 2u, &a0, &b0);
    tf2x32(0u, 42u, 1u, 3u, &a1, &b1);
    k1a = a0; k1b = a1; k2a = b0; k2b = b1;
  }
#endif

  // ---- CSR for the 3 edge sets (dst = row 1 of edge_index) ----
  const int* esets[3] = {eN, eR0, eR1};
  for (int s = 0; s < 3; s++) {
    int* rp = rowptrAll + s * (NN + 1);
    int* cl = colAll + (size_t)s * EE;
    hipMemsetAsync(counts, 0, NN * sizeof(int), stream);
    hist_kernel<<<EE / 256, 256, 0, stream>>>(esets[s] + EE, counts);
    scan_kernel<<<1, 1024, 0, stream>>>(counts, rp, cursor);
    scatter_kernel<<<EE / 256, 256, 0, stream>>>(esets[s], esets[s] + EE, cursor, cl);
  }

  // ---- 5 GAT layers; edge-set per layer: n, r1, r0, r1, r0 -> sets {0,2,1,2,1} ----
  struct Layer { const float* in; float* o; const float *Wl, *bl, *Wa, *ba; int set; };
  Layer Ls[5] = {
      {x,    bufA, W0l, b0l, W0a, b0a, 0},
      {bufA, bufB, W1l, b1l, W1a, b1a, 2},
      {bufB, bufA, W2l, b2l, W2a, b2a, 1},
      {bufA, bufB, W1l, b1l, W1a, b1a, 2},
      {bufB, bufA, W2l, b2l, W2a, b2a, 1},
  };
  for (int L = 0; L < 5; L++) {
    gemm128_kernel<<<NN / 64, 256, 0, stream>>>(Ls[L].in, Ls[L].Wl, Ls[L].bl, hb, 1);
    // P = h @ Wa[:128] + ba  (dst term, bias folded here); Q = h @ Wa[128:]  (src term)
    gemm128_kernel<<<NN / 64, 256, 0, stream>>>(hb, Ls[L].Wa, Ls[L].ba, Pb, 1);
    gemm128_kernel<<<NN / 64, 256, 0, stream>>>(hb, Ls[L].Wa + 128 * 128, nullptr, Qb, 0);
    gat_edge_kernel<<<NN / 4, 256, 0, stream>>>(
        Pb, Qb, hb, rowptrAll + Ls[L].set * (NN + 1),
        colAll + (size_t)Ls[L].set * EE, Ls[L].o);
  }
  const float* X = bufA;  // g4

  // ---- heads ----
  gemm128_kernel<<<NN / 64, 256, 0, stream>>>(X, Wa2, nullptr, Pb, 0);  // Y = X @ Wa2
  logits_kernel<<<NN / 4, 256, 0, stream>>>(X, Wp, bp, logits);
  hmean_kernel<<<NB, 1024, 0, stream>>>(X, out);
  sample1_kernel<<<NB, 256, 0, stream>>>(logits, k1a, k1b, idx1b, p1b, out);
  zk_kernel<<<NB, 128, 0, stream>>>(X, Wa1, idx1b, Zb);
  u_kernel<<<NN / 4, 256, 0, stream>>>(Pb, Zb, vt, idx1b, ub);
  sample2_kernel<<<NB, 256, 0, stream>>>(ub, k2a, k2b, p1b, out);
}

// Round 6
// 788.652 us; speedup vs baseline: 1.7423x; 1.1447x over previous
//
#include <hip/hip_runtime.h>
#include <stdint.h>
#include <math.h>

#define NN 32768      // total nodes
#define EE 262144     // edges per edge set (before self loops)
#define DD 128
#define NPG 1024
#define NB 32
#define NEG_SLOPE 0.2f
#define ATP 132       // A^T LDS pitch: 132 -> transpose-write banks spread (4k+4rg mod 32)
#define USE_PARTITIONABLE 1

// ---------------- threefry2x32 (exact JAX algorithm) ----------------
__host__ __device__ inline void tf2x32(uint32_t k0, uint32_t k1, uint32_t c0, uint32_t c1,
                                       uint32_t* o0, uint32_t* o1) {
  uint32_t ks2 = k0 ^ k1 ^ 0x1BD11BDAu;
  uint32_t x0 = c0 + k0;
  uint32_t x1 = c1 + k1;
#define TFR(r) { x0 += x1; x1 = (x1 << (r)) | (x1 >> (32 - (r))); x1 ^= x0; }
  TFR(13) TFR(15) TFR(26) TFR(6)
  x0 += k1; x1 += ks2 + 1u;
  TFR(17) TFR(29) TFR(16) TFR(24)
  x0 += ks2; x1 += k0 + 2u;
  TFR(13) TFR(15) TFR(26) TFR(6)
  x0 += k0; x1 += k1 + 3u;
  TFR(17) TFR(29) TFR(16) TFR(24)
  x0 += k1; x1 += ks2 + 4u;
  TFR(13) TFR(15) TFR(26) TFR(6)
  x0 += ks2; x1 += k0 + 5u;
#undef TFR
  *o0 = x0; *o1 = x1;
}

__device__ inline float gumbel_from_bits(uint32_t bits) {
  float fl = __uint_as_float((bits >> 9) | 0x3f800000u) - 1.0f;
  const float tiny = 1.17549435e-38f;
  float u = fmaxf(tiny, fl + tiny);
  return -logf(-logf(u));
}

__device__ inline float gumbel_at(uint32_t ka, uint32_t kb, uint32_t f) {
#if USE_PARTITIONABLE
  uint32_t o0, o1;
  tf2x32(ka, kb, 0u, f, &o0, &o1);   // counter = 64-bit flat index (hi=0, lo=f)
  return gumbel_from_bits(o0 ^ o1);  // 32-bit draw = XOR fold of both words
#else
  const uint32_t HALF = 16368u;
  uint32_t o0, o1;
  if (f < HALF) { tf2x32(ka, kb, f, f + HALF, &o0, &o1); return gumbel_from_bits(o0); }
  else          { tf2x32(ka, kb, f - HALF, f, &o0, &o1); return gumbel_from_bits(o1); }
#endif
}

// ---------------- batched CSR build (3 edge sets in one launch each) ----------------
__global__ __launch_bounds__(256) void hist3_kernel(const int* __restrict__ e0,
                                                    const int* __restrict__ e1,
                                                    const int* __restrict__ e2,
                                                    int* __restrict__ counts3) {
  int s = blockIdx.x >> 10;
  int i = (blockIdx.x & 1023) * 256 + threadIdx.x;
  const int* d = (s == 0) ? e0 : (s == 1) ? e1 : e2;
  atomicAdd(&counts3[s * NN + d[i + EE]], 1);  // dst row = second EE ints
}

__global__ __launch_bounds__(1024) void scan3_kernel(const int* __restrict__ counts3,
                                                     int* __restrict__ rowptrAll,
                                                     int* __restrict__ cursorAll) {
  __shared__ int part[1024];
  int s = blockIdx.x;
  const int* counts = counts3 + s * NN;
  int* rowptr = rowptrAll + s * (NN + 1);
  int* cursor = cursorAll + s * NN;
  int t = threadIdx.x;
  int base = t * 32;
  int local[32];
  {
    const int4* c4 = (const int4*)(counts + base);
    int sum = 0;
#pragma unroll
    for (int v = 0; v < 8; v++) {
      int4 cc = c4[v];
      local[v * 4 + 0] = sum; sum += cc.x;
      local[v * 4 + 1] = sum; sum += cc.y;
      local[v * 4 + 2] = sum; sum += cc.z;
      local[v * 4 + 3] = sum; sum += cc.w;
    }
    part[t] = sum;
  }
  __syncthreads();
  int own = part[t];
  for (int off = 1; off < 1024; off <<= 1) {
    int v = (t >= off) ? part[t - off] : 0;
    __syncthreads();
    part[t] += v;
    __syncthreads();
  }
  int excl = part[t] - own;
  {
    int4* rp4 = (int4*)(rowptr + base);
    int4* cu4 = (int4*)(cursor + base);
#pragma unroll
    for (int v = 0; v < 8; v++) {
      int4 w;
      w.x = excl + local[v * 4 + 0];
      w.y = excl + local[v * 4 + 1];
      w.z = excl + local[v * 4 + 2];
      w.w = excl + local[v * 4 + 3];
      rp4[v] = w;
      cu4[v] = w;
    }
  }
  if (t == 1023) rowptr[NN] = part[1023];
}

__global__ __launch_bounds__(256) void scatter3_kernel(const int* __restrict__ e0,
                                                       const int* __restrict__ e1,
                                                       const int* __restrict__ e2,
                                                       int* __restrict__ cursorAll,
                                                       int* __restrict__ colAll) {
  int s = blockIdx.x >> 10;
  int i = (blockIdx.x & 1023) * 256 + threadIdx.x;
  const int* e = (s == 0) ? e0 : (s == 1) ? e1 : e2;
  int src = e[i], dst = e[i + EE];
  int p = atomicAdd(&cursorAll[s * NN + dst], 1);
  colAll[(size_t)s * EE + p] = src;
}

// ---------------- fp32 GEMM (kept for the single head GEMM Y = X @ Wa2) ----------------
__global__ __launch_bounds__(256) void gemm128_kernel(const float* __restrict__ in,
                                                      const float* __restrict__ W,
                                                      const float* __restrict__ bias,
                                                      float* __restrict__ out, int hasBias) {
  __shared__ __align__(16) float ws[128 * 128];
  __shared__ __align__(16) float ins[64][132];
  int t = threadIdx.x;
  size_t row0 = (size_t)blockIdx.x * 64;
  {
    const float4* W4 = (const float4*)W;
    float4* ws4 = (float4*)ws;
#pragma unroll
    for (int i = 0; i < 16; i++) ws4[t + 256 * i] = W4[t + 256 * i];
    const float4* in4 = (const float4*)(in + row0 * 128);
#pragma unroll
    for (int i = 0; i < 8; i++) {
      int idx = t + 256 * i;
      int r = idx >> 5, c4 = idx & 31;
      float4 v = in4[(size_t)r * 32 + c4];
      *(float4*)&ins[r][c4 * 4] = v;
    }
  }
  __syncthreads();
  int cg = t & 15, rg = t >> 4;
  int c0 = cg * 8, r0 = rg * 4;
  float acc[4][8] = {};
#pragma unroll 8
  for (int k = 0; k < 128; k++) {
    float4 wA = *(const float4*)&ws[k * 128 + c0];
    float4 wB = *(const float4*)&ws[k * 128 + c0 + 4];
    float av[4];
    av[0] = ins[r0 + 0][k]; av[1] = ins[r0 + 1][k];
    av[2] = ins[r0 + 2][k]; av[3] = ins[r0 + 3][k];
#pragma unroll
    for (int i = 0; i < 4; i++) {
      acc[i][0] += av[i] * wA.x; acc[i][1] += av[i] * wA.y;
      acc[i][2] += av[i] * wA.z; acc[i][3] += av[i] * wA.w;
      acc[i][4] += av[i] * wB.x; acc[i][5] += av[i] * wB.y;
      acc[i][6] += av[i] * wB.z; acc[i][7] += av[i] * wB.w;
    }
  }
  float bb[8];
#pragma unroll
  for (int j = 0; j < 8; j++) bb[j] = hasBias ? bias[c0 + j] : 0.0f;
#pragma unroll
  for (int i = 0; i < 4; i++) {
    float* orow = out + (row0 + r0 + i) * 128 + c0;
    float4 o0, o1;
    o0.x = acc[i][0] + bb[0]; o0.y = acc[i][1] + bb[1];
    o0.z = acc[i][2] + bb[2]; o0.w = acc[i][3] + bb[3];
    o1.x = acc[i][4] + bb[4]; o1.y = acc[i][5] + bb[5];
    o1.z = acc[i][6] + bb[6]; o1.w = acc[i][7] + bb[7];
    *(float4*)orow = o0;
    *(float4*)(orow + 4) = o1;
  }
}

// ---------------- fused layer GEMM: h = in@Wl+bl; P = h@Wa_top+ba; Q = h@Wa_bot ----------
// 128-row tile per block, 256 threads, 8x8 thread tile, both operands via ds_read_b128.
// A^T staged in LDS (pitch ATP); W (64KB) resident in LDS. h^T restaged from registers.
__global__ __launch_bounds__(256, 1) void fused_layer_kernel(
    const float* __restrict__ in, const float* __restrict__ Wl,
    const float* __restrict__ bl, const float* __restrict__ Wa,
    const float* __restrict__ ba, float* __restrict__ h,
    float* __restrict__ P, float* __restrict__ Q) {
  __shared__ __align__(16) float at[128 * ATP];   // A^T (and later h^T)
  __shared__ __align__(16) float ws[128 * 128];   // staging: in_rm / W / h_rm
  int t = threadIdx.x;
  size_t row0 = (size_t)blockIdx.x * 128;
  int tr = t >> 4, tc = t & 15;
  int r0 = tr * 8, c0 = tc * 8;
  float acc[8][8];

  auto stage_ws = [&](const float* src) {  // 64KB row-major into ws, coalesced
    const float4* s4 = (const float4*)src;
    float4* d4 = (float4*)ws;
#pragma unroll
    for (int i = 0; i < 16; i++) d4[t + 256 * i] = s4[t + 256 * i];
  };
  auto transpose_ws_to_at = [&]() {  // at[k][r] = ws[r][k]
#pragma unroll
    for (int i = 0; i < 16; i++) {
      int idx = t + 256 * i;
      int k = idx & 127;
      int rg = idx >> 7;  // 0..31 (4 rows each)
      float4 v;
      v.x = ws[(rg * 4 + 0) * 128 + k];
      v.y = ws[(rg * 4 + 1) * 128 + k];
      v.z = ws[(rg * 4 + 2) * 128 + k];
      v.w = ws[(rg * 4 + 3) * 128 + k];
      *(float4*)&at[k * ATP + rg * 4] = v;
    }
  };
  auto mm = [&](const float* bias) {  // acc = at^T-block @ ws-block (+bias cols)
#pragma unroll
    for (int i = 0; i < 8; i++)
#pragma unroll
      for (int j = 0; j < 8; j++) acc[i][j] = 0.f;
#pragma unroll 2
    for (int k = 0; k < 128; k++) {
      float4 a0 = *(const float4*)&at[k * ATP + r0];
      float4 a1 = *(const float4*)&at[k * ATP + r0 + 4];
      float4 w0 = *(const float4*)&ws[k * 128 + c0];
      float4 w1 = *(const float4*)&ws[k * 128 + c0 + 4];
      float av[8] = {a0.x, a0.y, a0.z, a0.w, a1.x, a1.y, a1.z, a1.w};
      float wv[8] = {w0.x, w0.y, w0.z, w0.w, w1.x, w1.y, w1.z, w1.w};
#pragma unroll
      for (int i = 0; i < 8; i++)
#pragma unroll
        for (int j = 0; j < 8; j++) acc[i][j] += av[i] * wv[j];
    }
    if (bias) {
#pragma unroll
      for (int j = 0; j < 8; j++) {
        float b = bias[c0 + j];
#pragma unroll
        for (int i = 0; i < 8; i++) acc[i][j] += b;
      }
    }
  };
  auto writeout = [&](float* dst) {
#pragma unroll
    for (int i = 0; i < 8; i++) {
      float* orow = dst + (row0 + r0 + i) * DD + c0;
      float4 o0, o1;
      o0.x = acc[i][0]; o0.y = acc[i][1]; o0.z = acc[i][2]; o0.w = acc[i][3];
      o1.x = acc[i][4]; o1.y = acc[i][5]; o1.z = acc[i][6]; o1.w = acc[i][7];
      *(float4*)orow = o0;
      *(float4*)(orow + 4) = o1;
    }
  };

  stage_ws(in + row0 * DD);            // s1: in rows -> ws (row-major)
  __syncthreads();
  transpose_ws_to_at();                // s2: at = in^T
  __syncthreads();
  stage_ws(Wl);                        // s3
  __syncthreads();
  mm(bl);                              // s4: h-tile (bias folded into acc)
  writeout(h);
  __syncthreads();
  {                                    // s5: h regs -> ws row-major (no global re-read)
#pragma unroll
    for (int i = 0; i < 8; i++) {
      float4 o0, o1;
      o0.x = acc[i][0]; o0.y = acc[i][1]; o0.z = acc[i][2]; o0.w = acc[i][3];
      o1.x = acc[i][4]; o1.y = acc[i][5]; o1.z = acc[i][6]; o1.w = acc[i][7];
      *(float4*)&ws[(r0 + i) * 128 + c0] = o0;
      *(float4*)&ws[(r0 + i) * 128 + c0 + 4] = o1;
    }
  }
  __syncthreads();
  transpose_ws_to_at();                // s6: at = h^T
  __syncthreads();
  stage_ws(Wa);                        // s7: Wa_top (rows 0..127)
  __syncthreads();
  mm(ba);                              // s8: P
  writeout(P);
  __syncthreads();
  stage_ws(Wa + 128 * 128);            // s9: Wa_bot
  __syncthreads();
  mm(nullptr);                         // s10: Q
  writeout(Q);
}

// ---------------- fused GAT edge kernel (unchanged from R4, 47us) ----------------
__device__ inline float lk1(float v) { return v > 0.f ? v : NEG_SLOPE * v; }

__global__ __launch_bounds__(256, 4) void gat_edge_kernel(const float* __restrict__ P,
                                                          const float* __restrict__ Q,
                                                          const float* __restrict__ H,
                                                          const int* __restrict__ rowptr,
                                                          const int* __restrict__ col,
                                                          float* __restrict__ out) {
  int wv = threadIdx.x >> 6;
  int lane = threadIdx.x & 63;
  int dst = (blockIdx.x << 2) + wv;
  int rs = __builtin_amdgcn_readfirstlane(rowptr[dst]);
  int re = __builtin_amdgcn_readfirstlane(rowptr[dst + 1]);
  int deg = re - rs;
  int total = deg + 1;  // + self loop, appended last like the reference
  float2 pd = ((const float2*)(P + (size_t)dst * DD))[lane];

  float mx = -INFINITY, my = -INFINITY;
  float sx = 0.f, sy = 0.f;
  float cx = 0.f, cy = 0.f;

  for (int base = 0; base < total; base += 64) {
    int cnt = min(64, total - base);
    int e = base + lane;
    int myidx = (e < deg) ? col[rs + e] : dst;
    int i = 0;
    for (; i + 4 <= cnt; i += 4) {
      int iu = __builtin_amdgcn_readfirstlane(i);
      int n0 = __builtin_amdgcn_readlane(myidx, iu);
      int n1 = __builtin_amdgcn_readlane(myidx, iu + 1);
      int n2 = __builtin_amdgcn_readlane(myidx, iu + 2);
      int n3 = __builtin_amdgcn_readlane(myidx, iu + 3);
      float2 q0 = ((const float2*)(Q + (size_t)n0 * DD))[lane];
      float2 q1 = ((const float2*)(Q + (size_t)n1 * DD))[lane];
      float2 q2 = ((const float2*)(Q + (size_t)n2 * DD))[lane];
      float2 q3 = ((const float2*)(Q + (size_t)n3 * DD))[lane];
      float2 h0 = ((const float2*)(H + (size_t)n0 * DD))[lane];
      float2 h1 = ((const float2*)(H + (size_t)n1 * DD))[lane];
      float2 h2 = ((const float2*)(H + (size_t)n2 * DD))[lane];
      float2 h3 = ((const float2*)(H + (size_t)n3 * DD))[lane];
      float a0x = lk1(pd.x + q0.x), a0y = lk1(pd.y + q0.y);
      float a1x = lk1(pd.x + q1.x), a1y = lk1(pd.y + q1.y);
      float a2x = lk1(pd.x + q2.x), a2y = lk1(pd.y + q2.y);
      float a3x = lk1(pd.x + q3.x), a3y = lk1(pd.y + q3.y);
      float nmx = fmaxf(fmaxf(mx, fmaxf(a0x, a1x)), fmaxf(a2x, a3x));
      float nmy = fmaxf(fmaxf(my, fmaxf(a0y, a1y)), fmaxf(a2y, a3y));
      float scx = expf(mx - nmx), scy = expf(my - nmy);
      float e0x = expf(a0x - nmx), e1x = expf(a1x - nmx);
      float e2x = expf(a2x - nmx), e3x = expf(a3x - nmx);
      float e0y = expf(a0y - nmy), e1y = expf(a1y - nmy);
      float e2y = expf(a2y - nmy), e3y = expf(a3y - nmy);
      sx = sx * scx + ((e0x + e1x) + (e2x + e3x));
      sy = sy * scy + ((e0y + e1y) + (e2y + e3y));
      cx = cx * scx + ((e0x * h0.x + e1x * h1.x) + (e2x * h2.x + e3x * h3.x));
      cy = cy * scy + ((e0y * h0.y + e1y * h1.y) + (e2y * h2.y + e3y * h3.y));
      mx = nmx; my = nmy;
    }
    for (; i < cnt; i++) {
      int iu = __builtin_amdgcn_readfirstlane(i);
      int n0 = __builtin_amdgcn_readlane(myidx, iu);
      float2 q0 = ((const float2*)(Q + (size_t)n0 * DD))[lane];
      float2 h0 = ((const float2*)(H + (size_t)n0 * DD))[lane];
      float a0x = lk1(pd.x + q0.x), a0y = lk1(pd.y + q0.y);
      float nmx = fmaxf(mx, a0x), nmy = fmaxf(my, a0y);
      float scx = expf(mx - nmx), scy = expf(my - nmy);
      float e0x = expf(a0x - nmx), e0y = expf(a0y - nmy);
      sx = sx * scx + e0x;
      sy = sy * scy + e0y;
      cx = cx * scx + e0x * h0.x;
      cy = cy * scy + e0y * h0.y;
      mx = nmx; my = nmy;
    }
  }
  float2 o = make_float2(cx / (sx + 1e-16f), cy / (sy + 1e-16f));
  ((float2*)(out + (size_t)dst * DD))[lane] = o;
}

// ---------------- final stage ----------------
__global__ __launch_bounds__(256) void logits_kernel(const float* __restrict__ X,
                                                     const float* __restrict__ Wp,
                                                     const float* __restrict__ bp,
                                                     float* __restrict__ logits) {
  int w = threadIdx.x >> 6, lane = threadIdx.x & 63;
  int n = blockIdx.x * 4 + w;
  const float* xr = X + (size_t)n * DD;
  float p = xr[lane] * Wp[lane] + xr[lane + 64] * Wp[lane + 64];
  for (int off = 32; off > 0; off >>= 1) p += __shfl_down(p, off);
  if (lane == 0) logits[n] = p + bp[0];
}

__global__ __launch_bounds__(1024) void hmean_kernel(const float* __restrict__ X,
                                                     float* __restrict__ out) {
  int b = blockIdx.x;
  int t = threadIdx.x;
  int c = t & 127, part = t >> 7;
  float acc = 0.f;
  for (int i = part; i < NPG; i += 8)
    acc += X[((size_t)b * NPG + i) * DD + c];
  __shared__ float red[1024];
  red[t] = acc; __syncthreads();
  if (part == 0) {
    float s = 0.f;
#pragma unroll
    for (int p = 0; p < 8; p++) s += red[p * 128 + c];
    out[b * DD + c] = s * (1.0f / (float)NPG);
  }
}

__global__ __launch_bounds__(256) void sample1_kernel(const float* __restrict__ logits,
                                                      uint32_t ka, uint32_t kb,
                                                      int* __restrict__ idx1_ws,
                                                      float* __restrict__ p1_ws,
                                                      float* __restrict__ out) {
  int b = blockIdx.x, t = threadIdx.x;
  __shared__ float sV[256]; __shared__ int sJ[256]; __shared__ float sM[256];
  float bestV = -INFINITY; int bestJ = 1 << 30; float maxL = -INFINITY;
  for (int j = 1 + t; j < NPG; j += 256) {
    float l = logits[(size_t)b * NPG + j];
    maxL = fmaxf(maxL, l);
    float v = l + gumbel_at(ka, kb, (uint32_t)(b * 1023 + j - 1));
    if (v > bestV) { bestV = v; bestJ = j; }
  }
  sV[t] = bestV; sJ[t] = bestJ; sM[t] = maxL; __syncthreads();
  for (int off = 128; off > 0; off >>= 1) {
    if (t < off) {
      if (sV[t + off] > sV[t] || (sV[t + off] == sV[t] && sJ[t + off] < sJ[t])) {
        sV[t] = sV[t + off]; sJ[t] = sJ[t + off];
      }
      sM[t] = fmaxf(sM[t], sM[t + off]);
    }
    __syncthreads();
  }
  float M = sM[0]; int idx = sJ[0];
  __syncthreads();
  float ps = 0.f;
  for (int j = 1 + t; j < NPG; j += 256)
    ps += expf(logits[(size_t)b * NPG + j] - M);
  sV[t] = ps; __syncthreads();
  for (int off = 128; off > 0; off >>= 1) {
    if (t < off) sV[t] += sV[t + off];
    __syncthreads();
  }
  if (t == 0) {
    float S = sV[0];
    float p1 = expf(logits[(size_t)b * NPG + idx] - M) / S;
    idx1_ws[b] = idx;
    p1_ws[b] = p1;
    out[NB * DD + b] = (float)idx;  // index1
  }
}

__global__ __launch_bounds__(128) void zk_kernel(const float* __restrict__ X,
                                                 const float* __restrict__ Wa1,
                                                 const int* __restrict__ idx1,
                                                 float* __restrict__ Z) {
  int b = blockIdx.x, c = threadIdx.x;
  __shared__ float xs[128];
  int node = b * NPG + idx1[b];
  xs[c] = X[(size_t)node * DD + c];
  __syncthreads();
  float acc = 0.f;
#pragma unroll 8
  for (int k = 0; k < 128; k++) acc += xs[k] * Wa1[k * 128 + c];
  Z[b * DD + c] = acc;
}

__global__ __launch_bounds__(256) void u_kernel(const float* __restrict__ Y,
                                                const float* __restrict__ Z,
                                                const float* __restrict__ vt,
                                                const int* __restrict__ idx1,
                                                float* __restrict__ u) {
  int w = threadIdx.x >> 6, lane = threadIdx.x & 63;
  int n = blockIdx.x * 4 + w;
  int b = n >> 10;
  float t0 = tanhf(Z[b * DD + lane] + Y[(size_t)n * DD + lane]) * vt[lane];
  float t1 = tanhf(Z[b * DD + lane + 64] + Y[(size_t)n * DD + lane + 64]) * vt[lane + 64];
  float p = t0 + t1;
  for (int off = 32; off > 0; off >>= 1) p += __shfl_down(p, off);
  if (lane == 0) u[n] = ((n & (NPG - 1)) == idx1[b]) ? -INFINITY : p;
}

__global__ __launch_bounds__(256) void sample2_kernel(const float* __restrict__ u,
                                                      uint32_t ka, uint32_t kb,
                                                      const float* __restrict__ p1_ws,
                                                      float* __restrict__ out) {
  int b = blockIdx.x, t = threadIdx.x;
  __shared__ float sV[256]; __shared__ int sJ[256]; __shared__ float sM[256];
  float bestV = -INFINITY; int bestJ = 1 << 30; float maxL = -INFINITY;
  for (int j = 1 + t; j < NPG; j += 256) {
    float l = u[(size_t)b * NPG + j];
    maxL = fmaxf(maxL, l);
    float v = l + gumbel_at(ka, kb, (uint32_t)(b * 1023 + j - 1));
    if (v > bestV) { bestV = v; bestJ = j; }
  }
  sV[t] = bestV; sJ[t] = bestJ; sM[t] = maxL; __syncthreads();
  for (int off = 128; off > 0; off >>= 1) {
    if (t < off) {
      if (sV[t + off] > sV[t] || (sV[t + off] == sV[t] && sJ[t + off] < sJ[t])) {
        sV[t] = sV[t + off]; sJ[t] = sJ[t + off];
      }
      sM[t] = fmaxf(sM[t], sM[t + off]);
    }
    __syncthreads();
  }
  float M = sM[0]; int idx = sJ[0];
  __syncthreads();
  float ps = 0.f;
  for (int j = 1 + t; j < NPG; j += 256) {
    float l = u[(size_t)b * NPG + j];
    ps += expf(l - M);
  }
  sV[t] = ps; __syncthreads();
  for (int off = 128; off > 0; off >>= 1) {
    if (t < off) sV[t] += sV[t + off];
    __syncthreads();
  }
  if (t == 0) {
    float S = sV[0];
    float p2 = expf(u[(size_t)b * NPG + idx] - M) / S;
    out[NB * DD + NB + b] = (float)idx;                 // index2
    out[NB * DD + 2 * NB + b] = logf(p1_ws[b] + p2);    // log_probs
  }
}

// ---------------- host launcher ----------------
extern "C" void kernel_launch(void* const* d_in, const int* in_sizes, int n_in,
                              void* d_out, int out_size, void* d_ws, size_t ws_size,
                              hipStream_t stream) {
  const float* x  = (const float*)d_in[0];
  const int* eN   = (const int*)d_in[1];
  const int* eR0  = (const int*)d_in[2];
  const int* eR1  = (const int*)d_in[3];
  const float* W0l = (const float*)d_in[4];  const float* b0l = (const float*)d_in[5];
  const float* W0a = (const float*)d_in[6];  const float* b0a = (const float*)d_in[7];
  const float* W1l = (const float*)d_in[8];  const float* b1l = (const float*)d_in[9];
  const float* W1a = (const float*)d_in[10]; const float* b1a = (const float*)d_in[11];
  const float* W2l = (const float*)d_in[12]; const float* b2l = (const float*)d_in[13];
  const float* W2a = (const float*)d_in[14]; const float* b2a = (const float*)d_in[15];
  const float* Wp  = (const float*)d_in[16]; const float* bp  = (const float*)d_in[17];
  const float* Wa1 = (const float*)d_in[18]; const float* Wa2 = (const float*)d_in[19];
  const float* vt  = (const float*)d_in[20];
  float* out = (float*)d_out;

  char* wsb = (char*)d_ws;
  size_t off = 0;
  auto take = [&](size_t bytes) -> char* {
    char* p = wsb + off;
    off += (bytes + 255) & ~(size_t)255;
    return p;
  };
  int* rowptrAll = (int*)take((size_t)3 * (NN + 1) * sizeof(int));
  int* counts3   = (int*)take((size_t)3 * NN * sizeof(int));
  int* cursorAll = (int*)take((size_t)3 * NN * sizeof(int));
  int* colAll    = (int*)take((size_t)3 * EE * sizeof(int));
  float* bufA    = (float*)take((size_t)NN * DD * 4);
  float* bufB    = (float*)take((size_t)NN * DD * 4);
  float* hb      = (float*)take((size_t)NN * DD * 4);
  float* Pb      = (float*)take((size_t)NN * DD * 4);
  float* Qb      = (float*)take((size_t)NN * DD * 4);
  float* logits  = (float*)take((size_t)NN * 4);
  float* ub      = (float*)take((size_t)NN * 4);
  float* Zb      = (float*)take((size_t)NB * DD * 4);
  int* idx1b     = (int*)take(NB * 4);
  float* p1b     = (float*)take(NB * 4);

  // keys: jax.random.key(42) = (0,42); k1,k2 = split(key)
  uint32_t k1a, k1b, k2a, k2b;
#if USE_PARTITIONABLE
  {
    uint32_t o0, o1;
    tf2x32(0u, 42u, 0u, 0u, &o0, &o1); k1a = o0; k1b = o1;
    tf2x32(0u, 42u, 0u, 1u, &o0, &o1); k2a = o0; k2b = o1;
  }
#else
  {
    uint32_t a0, b0, a1, b1;
    tf2x32(0u, 42u, 0u, 2u, &a0, &b0);
    tf2x32(0u, 42u, 1u, 3u, &a1, &b1);
    k1a = a0; k1b = a1; k2a = b0; k2b = b1;
  }
#endif

  // ---- batched CSR build for the 3 edge sets ----
  hipMemsetAsync(counts3, 0, (size_t)3 * NN * sizeof(int), stream);
  hist3_kernel<<<3 * 1024, 256, 0, stream>>>(eN, eR0, eR1, counts3);
  scan3_kernel<<<3, 1024, 0, stream>>>(counts3, rowptrAll, cursorAll);
  scatter3_kernel<<<3 * 1024, 256, 0, stream>>>(eN, eR0, eR1, cursorAll, colAll);

  // ---- 5 GAT layers; edge-set per layer: n, r1, r0, r1, r0 -> sets {0,2,1,2,1} ----
  struct Layer { const float* in; float* o; const float *Wl, *bl, *Wa, *ba; int set; };
  Layer Ls[5] = {
      {x,    bufA, W0l, b0l, W0a, b0a, 0},
      {bufA, bufB, W1l, b1l, W1a, b1a, 2},
      {bufB, bufA, W2l, b2l, W2a, b2a, 1},
      {bufA, bufB, W1l, b1l, W1a, b1a, 2},
      {bufB, bufA, W2l, b2l, W2a, b2a, 1},
  };
  for (int L = 0; L < 5; L++) {
    fused_layer_kernel<<<NN / 128, 256, 0, stream>>>(
        Ls[L].in, Ls[L].Wl, Ls[L].bl, Ls[L].Wa, Ls[L].ba, hb, Pb, Qb);
    gat_edge_kernel<<<NN / 4, 256, 0, stream>>>(
        Pb, Qb, hb, rowptrAll + Ls[L].set * (NN + 1),
        colAll + (size_t)Ls[L].set * EE, Ls[L].o);
  }
  const float* X = bufA;  // g4

  // ---- heads ----
  gemm128_kernel<<<NN / 64, 256, 0, stream>>>(X, Wa2, nullptr, Pb, 0);  // Y = X @ Wa2
  logits_kernel<<<NN / 4, 256, 0, stream>>>(X, Wp, bp, logits);
  hmean_kernel<<<NB, 1024, 0, stream>>>(X, out);
  sample1_kernel<<<NB, 256, 0, stream>>>(logits, k1a, k1b, idx1b, p1b, out);
  zk_kernel<<<NB, 128, 0, stream>>>(X, Wa1, idx1b, Zb);
  u_kernel<<<NN / 4, 256, 0, stream>>>(Pb, Zb, vt, idx1b, ub);
  sample2_kernel<<<NB, 256, 0, stream>>>(ub, k2a, k2b, p1b, out);
}